// Round 14
// baseline (3511.469 us; speedup 1.0000x reference)
//
#include <hip/hip_runtime.h>
#include <hip/hip_bf16.h>
#include <hip/hip_fp16.h>

typedef __attribute__((ext_vector_type(8))) short short8;
typedef __attribute__((ext_vector_type(4))) float f32x4;

#define TWARM 96
#define SOUT  24
#define WIN   24   // x staging window (timesteps per per-wave LDS window)
#define NWIN  (TWARM / WIN)
#define K1 1.44269504089f   // log2(e)
#define K2 2.88539008178f   // 2*log2(e)

static __device__ __forceinline__ short f2bf(float f) {
    __hip_bfloat16 h = __float2bfloat16(f);
    return *reinterpret_cast<short*>(&h);
}
static __device__ __forceinline__ float bf2f(short s) {
    unsigned u = ((unsigned)(unsigned short)s) << 16;
    return __builtin_bit_cast(float, u);
}

// One wave owns 16 batch rows for all 119 steps; waves fully independent after
// the single init barrier. Per step: Z' = -K*(x@W + b + H@U) via 32 MFMAs in
// four gate-group quarters (acc peak 16 regs). NO intra-wave fences this
// round: all h/x LDS traffic is same-wave, and the CDNA LDS pipe processes a
// wave's DS ops in program order (lgkmcnt is register-availability, which the
// compiler inserts automatically). Removing the asm "memory" fences lets the
// scheduler overlap step t's gate math with step t+1's LDS reads — attacking
// the ~315 us of measured dual-wave stall bubbles (r13 analysis).
__global__ void __launch_bounds__(256, 2)
lstm_ar_kernel(const float* __restrict__ gin, const float* __restrict__ gW,
               const float* __restrict__ gU, const float* __restrict__ gb,
               const float* __restrict__ gWd, const float* __restrict__ gbd,
               float* __restrict__ gout, int B)
{
    __shared__ __align__(16) short    U_lds[16384];        // 32 KB, swizzled B-frags
    __shared__ __align__(16) short    h_lds[4][16][72];    // 9 KB, per-wave padded
    __shared__ __align__(16) unsigned x_lds[4][16][WIN];   // 6 KB fp16-pair x; reused for preds
    __shared__ float wdc_lds[4][2][16];                    // 512 B

    const int tid  = threadIdx.x;
    const int wv   = tid >> 6;
    const int lane = tid & 63;
    const int c4   = lane & 15;   // MFMA col / A-row selector
    const int hi   = lane >> 4;   // MFMA k-group / C-row group

    // ---- stage U (coalesced read, swizzled LDS write, gate-scale folded) ----
    for (int idx = tid; idx < 16384; idx += 256) {
        int k = idx >> 8, col = idx & 255;
        float sc = ((col >> 6) == 2) ? -K2 : -K1;   // g columns get -2*log2e
        int dst = (((col >> 4) * 2 + (k >> 5)) * 4 + ((k & 31) >> 3)) * 128
                + (col & 15) * 8 + (k & 7);
        U_lds[dst] = f2bf(sc * gU[idx]);
    }
    // ---- Wd table ----
    if (tid < 128) {
        int tt = tid >> 5, j = (tid >> 4) & 1, cc = tid & 15;
        wdc_lds[tt][j][cc] = gWd[(tt * 16 + cc) * 2 + j];
    }

    // ---- per-lane constants: W and b packed fp16 (scale folded) ----
    unsigned Wp[16], Bp[8];
#pragma unroll
    for (int n = 0; n < 16; ++n) {
        int col = n * 16 + c4;
        float sc = (n >= 8 && n < 12) ? -K2 : -K1;
        __half2 wp = __floats2half2_rn(sc * gW[col], sc * gW[256 + col]);
        Wp[n] = __builtin_bit_cast(unsigned, wp);
    }
#pragma unroll
    for (int m = 0; m < 8; ++m) {
        int n0 = 2 * m, n1 = 2 * m + 1;
        float s0 = (n0 >= 8 && n0 < 12) ? -K2 : -K1;
        float s1 = (n1 >= 8 && n1 < 12) ? -K2 : -K1;
        __half2 bp = __floats2half2_rn(s0 * gb[n0 * 16 + c4], s1 * gb[n1 * 16 + c4]);
        Bp[m] = __builtin_bit_cast(unsigned, bp);
    }
    const float bd0 = gbd[0], bd1 = gbd[1];

    const int row0   = blockIdx.x * 64 + wv * 16;
    const bool active = (row0 + 15) < B;

    // zero this wave's h buffer
    for (int i = lane; i < 16 * 72; i += 64) (&h_lds[wv][0][0])[i] = 0;

    // ---- per-wave x window staging: 16 rows x WIN steps, fp16 pairs ----
    const int xrow = lane >> 2, xq = lane & 3;   // 4 lanes/row, 12 floats each
    auto stage_x = [&](int w) {
        const float* src = gin + (size_t)(row0 + xrow) * (TWARM * 2)
                         + w * (WIN * 2) + xq * 12;
#pragma unroll
        for (int m = 0; m < 3; ++m) {
            float4 v = *reinterpret_cast<const float4*>(src + m * 4);
            uint2 pk;
            pk.x = __builtin_bit_cast(unsigned, __floats2half2_rn(v.x, v.y));
            pk.y = __builtin_bit_cast(unsigned, __floats2half2_rn(v.z, v.w));
            *reinterpret_cast<uint2*>(&x_lds[wv][xrow][xq * 6 + m * 2]) = pk;
        }
        // same-wave write->read: LDS pipe is in-order per wave; compiler
        // inserts the register-availability lgkmcnt before first use.
    };

    if (active) stage_x(0);
    __syncthreads();    // the ONLY block barrier: U + wdc staged & visible
    if (!active) return;

    float c_[4][4];     // pre-scaled: c' = -K2 * c
#pragma unroll
    for (int tt = 0; tt < 4; ++tt)
#pragma unroll
        for (int r = 0; r < 4; ++r) c_[tt][r] = 0.f;

    const short* hptr  = &h_lds[wv][0][0] + c4 * 72 + hi * 8;     // A-frag read base
    short*       hwptr = &h_lds[wv][0][0] + (hi * 4) * 72 + c4;   // h write base
    const short* uptr  = U_lds + lane * 8;                        // B-frag read base

    float h_[4][4];     // live during decode only

    // ---- one LSTM step; acc is z' = -K*z; four gate-group quarters ----
    auto lstm_step = [&](const float x0[4], const float x1[4], bool save_h) {
        short8 a0v = *reinterpret_cast<const short8*>(hptr);
        short8 a1v = *reinterpret_cast<const short8*>(hptr + 32);
#pragma unroll
        for (int tt = 0; tt < 4; ++tt) {
            f32x4 acc[4];   // tiles n = tt, tt+4, tt+8, tt+12 -> i,f,g,o
#pragma unroll
            for (int j = 0; j < 4; ++j) {
                const int n = tt + 4 * j;
                __half2 wp = __builtin_bit_cast(__half2, Wp[n]);
                float w0 = __low2float(wp), w1 = __high2float(wp);
                __half2 bp = __builtin_bit_cast(__half2, Bp[n >> 1]);
                float bv = (n & 1) ? __high2float(bp) : __low2float(bp);
#pragma unroll
                for (int r = 0; r < 4; ++r)
                    acc[j][r] = fmaf(x1[r], w1, fmaf(x0[r], w0, bv));
            }
#pragma unroll
            for (int j = 0; j < 4; ++j) {
                const int n = tt + 4 * j;
                short8 u0 = *reinterpret_cast<const short8*>(uptr + (n * 2 + 0) * 512);
                short8 u1 = *reinterpret_cast<const short8*>(uptr + (n * 2 + 1) * 512);
                acc[j] = __builtin_amdgcn_mfma_f32_16x16x32_bf16(a0v, u0, acc[j], 0, 0, 0);
                acc[j] = __builtin_amdgcn_mfma_f32_16x16x32_bf16(a1v, u1, acc[j], 0, 0, 0);
            }
            // ea=e^{-zi}, ef=e^{-zf}, eg=e^{-2zg}, eo=e^{-zo}
            // c' update: c'n = sf*c' + (K2*eg - K2)*rcp((1+ea)(1+eg)); ec = exp2(c'n)
#pragma unroll
            for (int r = 0; r < 4; ++r) {
                float ea = __builtin_amdgcn_exp2f(acc[0][r]);
                float ef = __builtin_amdgcn_exp2f(acc[1][r]);
                float eg = __builtin_amdgcn_exp2f(acc[2][r]);
                float eo = __builtin_amdgcn_exp2f(acc[3][r]);
                float sf = __builtin_amdgcn_rcpf(1.0f + ef);
                float sg = fmaf(eg, K2, -K2) *
                    __builtin_amdgcn_rcpf((1.0f + ea) * (1.0f + eg));
                float cn = fmaf(sf, c_[tt][r], sg);
                c_[tt][r] = cn;
                float ec = __builtin_amdgcn_exp2f(cn);
                float hn = (1.0f - ec) *
                    __builtin_amdgcn_rcpf((1.0f + eo) * (1.0f + ec));
                if (save_h) h_[tt][r] = hn;
                hwptr[r * 72 + tt * 16] = f2bf(hn);
            }
        }
        // No fence: ds_write(h) -> next-step ds_read(h) is same-wave, same
        // buffer; program order is preserved by alias analysis and the LDS
        // pipe is in-order per wave. Compiler emits the minimal lgkmcnt
        // before the next step's first MFMA use of a0v/a1v.
    };

    // ---- warmup: 96 steps, x from this wave's LDS windows ----
#pragma unroll 1
    for (int w = 0; w < NWIN; ++w) {
        if (w != 0) stage_x(w);
#pragma unroll 1
        for (int tl = 0; tl < WIN; ++tl) {
            float x0[4], x1[4];
#pragma unroll
            for (int r = 0; r < 4; ++r) {
                __half2 hx = __builtin_bit_cast(__half2, x_lds[wv][hi * 4 + r][tl]);
                x0[r] = __low2float(hx);
                x1[r] = __high2float(hx);
            }
            lstm_step(x0, x1, false);
        }
    }

    // rebuild h_ (f32) from the bf16 LDS copy once after warmup
#pragma unroll
    for (int tt = 0; tt < 4; ++tt)
#pragma unroll
        for (int r = 0; r < 4; ++r)
            h_[tt][r] = bf2f((&h_lds[wv][0][0])[(hi * 4 + r) * 72 + tt * 16 + c4]);

    // hoist Wd for this lane's cols (decode-only registers)
    float wdc[4][2];
#pragma unroll
    for (int tt = 0; tt < 4; ++tt) {
        wdc[tt][0] = wdc_lds[tt][0][c4];
        wdc[tt][1] = wdc_lds[tt][1][c4];
    }

    // ---- decode: pred = h@Wd + bd, butterfly over the 16-lane col group ----
    auto make_pred = [&](float* p0, float* p1) {
#pragma unroll
        for (int r = 0; r < 4; ++r) {
            float a0 = 0.f, a1 = 0.f;
#pragma unroll
            for (int tt = 0; tt < 4; ++tt) {
                a0 = fmaf(h_[tt][r], wdc[tt][0], a0);
                a1 = fmaf(h_[tt][r], wdc[tt][1], a1);
            }
            p0[r] = a0; p1[r] = a1;
        }
#pragma unroll
        for (int m = 1; m < 16; m <<= 1)
#pragma unroll
            for (int r = 0; r < 4; ++r) {
                p0[r] += __shfl_xor(p0[r], m, 64);
                p1[r] += __shfl_xor(p1[r], m, 64);
            }
#pragma unroll
        for (int r = 0; r < 4; ++r) { p0[r] += bd0; p1[r] += bd1; }
    };
    // stash pred fp16 in this wave's (dead) x window; feedback stays f32 regs
    auto store_pred = [&](int s, const float* p0, const float* p1) {
        if (c4 == 0) {
#pragma unroll
            for (int r = 0; r < 4; ++r)
                x_lds[wv][hi * 4 + r][s] =
                    __builtin_bit_cast(unsigned, __floats2half2_rn(p0[r], p1[r]));
        }
    };

    float p0[4], p1[4];
    make_pred(p0, p1);
    store_pred(0, p0, p1);
#pragma unroll 1
    for (int s = 1; s < SOUT; ++s) {
        lstm_step(p0, p1, true);
        make_pred(p0, p1);
        store_pred(s, p0, p1);
    }
    // same-wave pred stash -> writeout read: in-order LDS pipe, no fence needed

    // ---- per-wave coalesced writeout: 16 rows x 48 floats ----
#pragma unroll
    for (int m = 0; m < 6; ++m) {
        unsigned u = x_lds[wv][xrow][xq * 6 + m];
        __half2 hv = __builtin_bit_cast(__half2, u);
        *reinterpret_cast<float2*>(
            gout + (size_t)(row0 + xrow) * (SOUT * 2) + xq * 12 + m * 2) =
            make_float2(__low2float(hv), __high2float(hv));
    }
}

extern "C" void kernel_launch(void* const* d_in, const int* in_sizes, int n_in,
                              void* d_out, int out_size, void* d_ws, size_t ws_size,
                              hipStream_t stream) {
    const float* gin  = (const float*)d_in[0];
    const float* gW   = (const float*)d_in[1];
    const float* gU   = (const float*)d_in[2];
    const float* gb   = (const float*)d_in[3];
    const float* gWd  = (const float*)d_in[4];
    const float* gbd  = (const float*)d_in[5];
    float* gout = (float*)d_out;

    const int B = in_sizes[0] / (TWARM * 2);
    const int blocks = (B + 63) / 64;
    lstm_ar_kernel<<<blocks, 256, 0, stream>>>(gin, gW, gU, gb, gWd, gbd, gout, B);
}

// Round 16
// 583.785 us; speedup vs baseline: 6.0150x; 6.0150x over previous
//
#include <hip/hip_runtime.h>
#include <hip/hip_bf16.h>

typedef __attribute__((ext_vector_type(8))) short short8;
typedef __attribute__((ext_vector_type(4))) float f32x4;

#define TWARM 96
#define SOUT  24
#define WIN   24   // x staging window (timesteps per per-wave LDS window)
#define XPS   25   // padded x_lds row stride in words (kills bank aliasing)
#define NWIN  (TWARM / WIN)
#define K1 1.44269504089f   // log2(e)
#define K2 2.88539008178f   // 2*log2(e)

// Intra-wave fence: LDS ordering AND (critically, r14 lesson) a scheduler
// region boundary that stops cross-step hoisting from exploding live ranges.
#define LGKM_FENCE() do { \
    asm volatile("s_waitcnt lgkmcnt(0)" ::: "memory"); \
    __builtin_amdgcn_sched_barrier(0); \
} while (0)

static __device__ __forceinline__ short f2bf(float f) {
    __hip_bfloat16 h = __float2bfloat16(f);
    return *reinterpret_cast<short*>(&h);
}
static __device__ __forceinline__ float bf2f(short s) {
    unsigned u = ((unsigned)(unsigned short)s) << 16;
    return __builtin_bit_cast(float, u);
}
static __device__ __forceinline__ unsigned pkbf(float lo, float hi) {
    return (unsigned)(unsigned short)f2bf(lo)
         | ((unsigned)(unsigned short)f2bf(hi) << 16);
}

// One wave owns 16 batch rows for all 119 steps; waves fully independent after
// the single init barrier (r7 structure, r10 tuning). NEW this round: the
// x@W + b rank-2 update moves off the VALU onto the idle MFMA pipe via a
// K-extension — each tile computes acc = (x,1)@(W;b) + H@U as THREE chained
// K=32 MFMAs. Virtual K-rows: {64:x0, 65:x1, 66:1.0}; U_lds holds a third
// B-fragment per tile with rows {W0, W1, b} (gate scales folded). A-frag for
// the third MFMA is built from ONE ds_read_b32 of bf16-packed x (row c4,
// hi==0 lanes only). Removes ~128 FMA + ~96 cvt per step (~15% of VALU issue).
__global__ void __attribute__((amdgpu_flat_work_group_size(256, 256),
                               amdgpu_waves_per_eu(2, 2)))
lstm_ar_kernel(const float* __restrict__ gin, const float* __restrict__ gW,
               const float* __restrict__ gU, const float* __restrict__ gb,
               const float* __restrict__ gWd, const float* __restrict__ gbd,
               float* __restrict__ gout, int B)
{
    __shared__ __align__(16) short    U_lds[24576];        // 48 KB: 16 tiles x 3 frags
    __shared__ __align__(16) short    h_lds[4][16][72];    // 9 KB, per-wave padded
    __shared__ __align__(16) unsigned x_lds[4][16][XPS];   // 6.25 KB bf16-pair x / preds
    __shared__ float wdc_lds[4][2][16];                    // 512 B

    const int tid  = threadIdx.x;
    const int wv   = tid >> 6;
    const int lane = tid & 63;
    const int c4   = lane & 15;   // MFMA col / A-row selector
    const int hi   = lane >> 4;   // MFMA k-group / C-row group

    // ---- stage U fragments 0,1 (H@U part; swizzled, gate-scale folded) ----
    for (int idx = tid; idx < 16384; idx += 256) {
        int k = idx >> 8, col = idx & 255;
        float sc = ((col >> 6) == 2) ? -K2 : -K1;   // g columns get -2*log2e
        int n = col >> 4, frag = k >> 5, sub = (k & 31) >> 3;
        int dst = (n * 3 + frag) * 512 + sub * 128 + (col & 15) * 8 + (k & 7);
        U_lds[dst] = f2bf(sc * gU[idx]);
    }
    // ---- stage U fragment 2 (x@W + b rows: k_v 0->W0, 1->W1, 2->b, else 0) ----
    for (int i = tid; i < 8192; i += 256) {
        int n = i >> 9, rem = i & 511, sub = rem >> 7, cc = (rem >> 3) & 15, e = i & 7;
        int col = n * 16 + cc;
        float sc = ((col >> 6) == 2) ? -K2 : -K1;
        float v = 0.f;
        if (sub == 0) {
            if (e == 0)      v = sc * gW[col];
            else if (e == 1) v = sc * gW[256 + col];
            else if (e == 2) v = sc * gb[col];
        }
        U_lds[(n * 3 + 2) * 512 + rem] = f2bf(v);
    }
    // ---- Wd table ----
    if (tid < 128) {
        int tt = tid >> 5, j = (tid >> 4) & 1, cc = tid & 15;
        wdc_lds[tt][j][cc] = gWd[(tt * 16 + cc) * 2 + j];
    }
    const float bd0 = gbd[0], bd1 = gbd[1];

    const int row0   = blockIdx.x * 64 + wv * 16;
    const bool active = (row0 + 15) < B;

    // zero this wave's h buffer
    for (int i = lane; i < 16 * 72; i += 64) (&h_lds[wv][0][0])[i] = 0;

    // ---- per-wave x window staging: 16 rows x WIN steps, bf16 pairs ----
    const int xrow = lane >> 2, xq = lane & 3;   // 4 lanes/row, 12 floats each
    auto stage_x = [&](int w) {
        const float* src = gin + (size_t)(row0 + xrow) * (TWARM * 2)
                         + w * (WIN * 2) + xq * 12;
#pragma unroll
        for (int m = 0; m < 3; ++m) {
            float4 v = *reinterpret_cast<const float4*>(src + m * 4);
            x_lds[wv][xrow][xq * 6 + m * 2 + 0] = pkbf(v.x, v.y);
            x_lds[wv][xrow][xq * 6 + m * 2 + 1] = pkbf(v.z, v.w);
        }
        LGKM_FENCE();   // window visible to this wave before first read
    };

    if (active) stage_x(0);
    __syncthreads();    // the ONLY block barrier: U + wdc staged & visible
    if (!active) return;

    float c_[4][4];     // pre-scaled: c' = -K2 * c
#pragma unroll
    for (int tt = 0; tt < 4; ++tt)
#pragma unroll
        for (int r = 0; r < 4; ++r) c_[tt][r] = 0.f;

    const short* hptr  = &h_lds[wv][0][0] + c4 * 72 + hi * 8;     // A-frag read base
    short*       hwptr = &h_lds[wv][0][0] + (hi * 4) * 72 + c4;   // h write base
    const short* uptr  = U_lds + lane * 8;                        // B-frag read base

    const f32x4 zero4 = {0.f, 0.f, 0.f, 0.f};   // loop-invariant MFMA C-init
    float h_[4][4];     // live during decode only

    // ---- one LSTM step; acc is z' = -K*z; four gate-group quarters.
    //      xp = bf16-packed (x0,x1) for row c4 (any value for hi!=0 lanes). ----
    auto lstm_step = [&](unsigned xp, bool save_h) {
        short8 a0v = *reinterpret_cast<const short8*>(hptr);
        short8 a1v = *reinterpret_cast<const short8*>(hptr + 32);
        short8 a2v = {0, 0, 0, 0, 0, 0, 0, 0};   // virtual K-rows {x0, x1, 1}
        if (hi == 0) {
            a2v[0] = (short)(xp & 0xFFFFu);
            a2v[1] = (short)(xp >> 16);
            a2v[2] = (short)0x3F80;              // bf16(1.0) multiplies b
        }
#pragma unroll
        for (int tt = 0; tt < 4; ++tt) {
            f32x4 acc[4];   // tiles n = tt, tt+4, tt+8, tt+12 -> i,f,g,o
#pragma unroll
            for (int j = 0; j < 4; ++j) {
                const int n = tt + 4 * j;
                short8 u2 = *reinterpret_cast<const short8*>(uptr + (n * 3 + 2) * 512);
                acc[j] = __builtin_amdgcn_mfma_f32_16x16x32_bf16(a2v, u2, zero4, 0, 0, 0);
            }
#pragma unroll
            for (int j = 0; j < 4; ++j) {
                const int n = tt + 4 * j;
                short8 u0 = *reinterpret_cast<const short8*>(uptr + (n * 3 + 0) * 512);
                short8 u1 = *reinterpret_cast<const short8*>(uptr + (n * 3 + 1) * 512);
                acc[j] = __builtin_amdgcn_mfma_f32_16x16x32_bf16(a0v, u0, acc[j], 0, 0, 0);
                acc[j] = __builtin_amdgcn_mfma_f32_16x16x32_bf16(a1v, u1, acc[j], 0, 0, 0);
            }
            // ea=e^{-zi}, ef=e^{-zf}, eg=e^{-2zg}, eo=e^{-zo}
            // c' update: c'n = sf*c' + (K2*eg - K2)*rcp((1+ea)(1+eg)); ec = exp2(c'n)
#pragma unroll
            for (int r = 0; r < 4; ++r) {
                float ea = __builtin_amdgcn_exp2f(acc[0][r]);
                float ef = __builtin_amdgcn_exp2f(acc[1][r]);
                float eg = __builtin_amdgcn_exp2f(acc[2][r]);
                float eo = __builtin_amdgcn_exp2f(acc[3][r]);
                float sf = __builtin_amdgcn_rcpf(1.0f + ef);
                float sg = fmaf(eg, K2, -K2) *
                    __builtin_amdgcn_rcpf((1.0f + ea) * (1.0f + eg));
                float cn = fmaf(sf, c_[tt][r], sg);
                c_[tt][r] = cn;
                float ec = __builtin_amdgcn_exp2f(cn);
                float hn = (1.0f - ec) *
                    __builtin_amdgcn_rcpf((1.0f + eo) * (1.0f + ec));
                if (save_h) h_[tt][r] = hn;
                hwptr[r * 72 + tt * 16] = f2bf(hn);
            }
        }
        LGKM_FENCE();   // h writes ordered before next step + sched region cap
    };

    // ---- warmup: 96 steps, x from this wave's LDS windows (1 read/step) ----
#pragma unroll 1
    for (int w = 0; w < NWIN; ++w) {
        if (w != 0) stage_x(w);   // prior step's fence ordered old-window reads
#pragma unroll 1
        for (int tl = 0; tl < WIN; ++tl)
            lstm_step(x_lds[wv][c4][tl], false);
    }

    // rebuild h_ (f32) from the bf16 LDS copy once after warmup
#pragma unroll
    for (int tt = 0; tt < 4; ++tt)
#pragma unroll
        for (int r = 0; r < 4; ++r)
            h_[tt][r] = bf2f((&h_lds[wv][0][0])[(hi * 4 + r) * 72 + tt * 16 + c4]);

    // hoist Wd for this lane's cols (decode-only registers)
    float wdc[4][2];
#pragma unroll
    for (int tt = 0; tt < 4; ++tt) {
        wdc[tt][0] = wdc_lds[tt][0][c4];
        wdc[tt][1] = wdc_lds[tt][1][c4];
    }

    // ---- decode: pred = h@Wd + bd, butterfly over the 16-lane col group ----
    auto make_pred = [&](float* p0, float* p1) {
#pragma unroll
        for (int r = 0; r < 4; ++r) {
            float a0 = 0.f, a1 = 0.f;
#pragma unroll
            for (int tt = 0; tt < 4; ++tt) {
                a0 = fmaf(h_[tt][r], wdc[tt][0], a0);
                a1 = fmaf(h_[tt][r], wdc[tt][1], a1);
            }
            p0[r] = a0; p1[r] = a1;
        }
#pragma unroll
        for (int m = 1; m < 16; m <<= 1)
#pragma unroll
            for (int r = 0; r < 4; ++r) {
                p0[r] += __shfl_xor(p0[r], m, 64);
                p1[r] += __shfl_xor(p1[r], m, 64);
            }
#pragma unroll
        for (int r = 0; r < 4; ++r) { p0[r] += bd0; p1[r] += bd1; }
    };
    // fetch row c4's pred from the lane group that owns it; pack bf16 pair
    auto build_xp = [&](const float* p0, const float* p1) -> unsigned {
        int srcl = (c4 >> 2) << 4;   // lane with hi = c4>>2 (col 0 of its group)
        float a  = __shfl(p0[0], srcl, 64), b2 = __shfl(p0[1], srcl, 64);
        float cc = __shfl(p0[2], srcl, 64), d  = __shfl(p0[3], srcl, 64);
        float e  = __shfl(p1[0], srcl, 64), f  = __shfl(p1[1], srcl, 64);
        float g  = __shfl(p1[2], srcl, 64), h2 = __shfl(p1[3], srcl, 64);
        int rr = c4 & 3;
        float q0 = (rr & 2) ? ((rr & 1) ? d  : cc) : ((rr & 1) ? b2 : a);
        float q1 = (rr & 2) ? ((rr & 1) ? h2 : g)  : ((rr & 1) ? f  : e);
        return pkbf(q0, q1);
    };
    // stash pred bf16 in this wave's (dead) x window for the final writeout
    auto store_pred = [&](int s, const float* p0, const float* p1) {
        if (c4 == 0) {
#pragma unroll
            for (int r = 0; r < 4; ++r)
                x_lds[wv][hi * 4 + r][s] = pkbf(p0[r], p1[r]);
        }
    };

    float p0[4], p1[4];
    make_pred(p0, p1);
    store_pred(0, p0, p1);
#pragma unroll 1
    for (int s = 1; s < SOUT; ++s) {
        lstm_step(build_xp(p0, p1), true);
        make_pred(p0, p1);
        store_pred(s, p0, p1);
    }
    LGKM_FENCE();   // all pred stashes of this wave visible to this wave

    // ---- per-wave coalesced writeout: 16 rows x 48 floats ----
#pragma unroll
    for (int m = 0; m < 6; ++m) {
        unsigned u = x_lds[wv][xrow][xq * 6 + m];
        *reinterpret_cast<float2*>(
            gout + (size_t)(row0 + xrow) * (SOUT * 2) + xq * 12 + m * 2) =
            make_float2(bf2f((short)(u & 0xFFFFu)), bf2f((short)(u >> 16)));
    }
}

extern "C" void kernel_launch(void* const* d_in, const int* in_sizes, int n_in,
                              void* d_out, int out_size, void* d_ws, size_t ws_size,
                              hipStream_t stream) {
    const float* gin  = (const float*)d_in[0];
    const float* gW   = (const float*)d_in[1];
    const float* gU   = (const float*)d_in[2];
    const float* gb   = (const float*)d_in[3];
    const float* gWd  = (const float*)d_in[4];
    const float* gbd  = (const float*)d_in[5];
    float* gout = (float*)d_out;

    const int B = in_sizes[0] / (TWARM * 2);
    const int blocks = (B + 63) / 64;
    lstm_ar_kernel<<<blocks, 256, 0, stream>>>(gin, gW, gU, gb, gWd, gbd, gout, B);
}

// Round 17
// 544.917 us; speedup vs baseline: 6.4440x; 1.0713x over previous
//
#include <hip/hip_runtime.h>
#include <hip/hip_bf16.h>

typedef __attribute__((ext_vector_type(8))) short short8;
typedef __attribute__((ext_vector_type(4))) float f32x4;

#define TWARM 96
#define SOUT  24
#define WIN   24   // x staging window (timesteps per per-wave LDS window)
#define XPS   25   // padded x_lds row stride in words (kills bank aliasing)
#define NWIN  (TWARM / WIN)
#define K1 1.44269504089f   // log2(e)
#define K2 2.88539008178f   // 2*log2(e)

// Intra-wave fence: LDS ordering AND (r14 lesson) a scheduler region boundary
// that stops cross-step hoisting from exploding live ranges.
#define LGKM_FENCE() do { \
    asm volatile("s_waitcnt lgkmcnt(0)" ::: "memory"); \
    __builtin_amdgcn_sched_barrier(0); \
} while (0)

static __device__ __forceinline__ short f2bf(float f) {
    __hip_bfloat16 h = __float2bfloat16(f);
    return *reinterpret_cast<short*>(&h);
}
static __device__ __forceinline__ float bf2f(short s) {
    unsigned u = ((unsigned)(unsigned short)s) << 16;
    return __builtin_bit_cast(float, u);
}
static __device__ __forceinline__ unsigned pkbf(float lo, float hi) {
    return (unsigned)(unsigned short)f2bf(lo)
         | ((unsigned)(unsigned short)f2bf(hi) << 16);
}

// r16 structure (x@W+b on the MFMA pipe via K-extension; VGPR=88, zero spill)
// + occupancy conversion: 8 waves/block share one U copy; frag-2 stored
// COMPACT (128 shorts/tile — lanes 16-63's B-rows are multiplied by zero A
// rows, so they may read duplicate/garbage values; (lane&15)*8 read = 4-way
// same-address broadcast, free). LDS 67 KB -> 2 blocks/CU = 16 waves/CU =
// 4 waves/SIMD; grid 512 = ALL blocks resident in one phase, zero tail.
// waves_per_eu(4,4): 128-reg budget >= the 88 this kernel needs.
__global__ void __attribute__((amdgpu_flat_work_group_size(512, 512),
                               amdgpu_waves_per_eu(4, 4)))
lstm_ar_kernel(const float* __restrict__ gin, const float* __restrict__ gW,
               const float* __restrict__ gU, const float* __restrict__ gb,
               const float* __restrict__ gWd, const float* __restrict__ gbd,
               float* __restrict__ gout, int B)
{
    __shared__ __align__(16) short    U_lds[16384];        // 32 KB: frag 0,1 (H@U)
    __shared__ __align__(16) short    U2_lds[2048];        // 4 KB: compact frag 2
    __shared__ __align__(16) short    h_lds[8][16][72];    // 18 KB, per-wave padded
    __shared__ __align__(16) unsigned x_lds[8][16][XPS];   // 12.5 KB bf16-pair x / preds
    __shared__ float wdc_lds[4][2][16];                    // 512 B

    const int tid  = threadIdx.x;
    const int wv   = tid >> 6;
    const int lane = tid & 63;
    const int c4   = lane & 15;   // MFMA col / A-row selector
    const int hi   = lane >> 4;   // MFMA k-group / C-row group

    // ---- stage U fragments 0,1 (H@U part; swizzled, gate-scale folded) ----
    for (int idx = tid; idx < 16384; idx += 512) {
        int k = idx >> 8, col = idx & 255;
        float sc = ((col >> 6) == 2) ? -K2 : -K1;   // g columns get -2*log2e
        int n = col >> 4, frag = k >> 5, sub = (k & 31) >> 3;
        int dst = (n * 2 + frag) * 512 + sub * 128 + (col & 15) * 8 + (k & 7);
        U_lds[dst] = f2bf(sc * gU[idx]);
    }
    // ---- stage compact U fragment 2: k_v 0->W0, 1->W1, 2->b, 3..7 -> 0 ----
    for (int i = tid; i < 2048; i += 512) {
        int n = i >> 7, cc = (i >> 3) & 15, e = i & 7;
        int col = n * 16 + cc;
        float sc = ((col >> 6) == 2) ? -K2 : -K1;
        float v = 0.f;
        if (e == 0)      v = sc * gW[col];
        else if (e == 1) v = sc * gW[256 + col];
        else if (e == 2) v = sc * gb[col];
        U2_lds[n * 128 + cc * 8 + e] = f2bf(v);
    }
    // ---- Wd table ----
    if (tid < 128) {
        int tt = tid >> 5, j = (tid >> 4) & 1, cc = tid & 15;
        wdc_lds[tt][j][cc] = gWd[(tt * 16 + cc) * 2 + j];
    }
    const float bd0 = gbd[0], bd1 = gbd[1];

    const int row0   = blockIdx.x * 128 + wv * 16;
    const bool active = (row0 + 15) < B;

    // zero this wave's h buffer
    for (int i = lane; i < 16 * 72; i += 64) (&h_lds[wv][0][0])[i] = 0;

    // ---- per-wave x window staging: 16 rows x WIN steps, bf16 pairs ----
    const int xrow = lane >> 2, xq = lane & 3;   // 4 lanes/row, 12 floats each
    auto stage_x = [&](int w) {
        const float* src = gin + (size_t)(row0 + xrow) * (TWARM * 2)
                         + w * (WIN * 2) + xq * 12;
#pragma unroll
        for (int m = 0; m < 3; ++m) {
            float4 v = *reinterpret_cast<const float4*>(src + m * 4);
            x_lds[wv][xrow][xq * 6 + m * 2 + 0] = pkbf(v.x, v.y);
            x_lds[wv][xrow][xq * 6 + m * 2 + 1] = pkbf(v.z, v.w);
        }
        LGKM_FENCE();   // window visible to this wave before first read
    };

    if (active) stage_x(0);
    __syncthreads();    // the ONLY block barrier: U + U2 + wdc staged & visible
    if (!active) return;

    float c_[4][4];     // pre-scaled: c' = -K2 * c
#pragma unroll
    for (int tt = 0; tt < 4; ++tt)
#pragma unroll
        for (int r = 0; r < 4; ++r) c_[tt][r] = 0.f;

    const short* hptr  = &h_lds[wv][0][0] + c4 * 72 + hi * 8;     // A-frag read base
    short*       hwptr = &h_lds[wv][0][0] + (hi * 4) * 72 + c4;   // h write base
    const short* uptr  = U_lds + lane * 8;                        // B-frag read base
    const short* uptr2 = U2_lds + c4 * 8;        // compact frag 2 (hi groups broadcast)

    const f32x4 zero4 = {0.f, 0.f, 0.f, 0.f};   // loop-invariant MFMA C-init
    float h_[4][4];     // live during decode only

    // ---- one LSTM step; acc is z' = -K*z; four gate-group quarters.
    //      xp = bf16-packed (x0,x1) for row c4 (any value for hi!=0 lanes). ----
    auto lstm_step = [&](unsigned xp, bool save_h) {
        short8 a0v = *reinterpret_cast<const short8*>(hptr);
        short8 a1v = *reinterpret_cast<const short8*>(hptr + 32);
        short8 a2v = {0, 0, 0, 0, 0, 0, 0, 0};   // virtual K-rows {x0, x1, 1}
        if (hi == 0) {
            a2v[0] = (short)(xp & 0xFFFFu);
            a2v[1] = (short)(xp >> 16);
            a2v[2] = (short)0x3F80;              // bf16(1.0) multiplies b
        }
#pragma unroll
        for (int tt = 0; tt < 4; ++tt) {
            f32x4 acc[4];   // tiles n = tt, tt+4, tt+8, tt+12 -> i,f,g,o
#pragma unroll
            for (int j = 0; j < 4; ++j) {
                const int n = tt + 4 * j;
                // compact frag 2: lanes with hi!=0 read duplicate rows — their
                // A rows are zero, so the values are don't-care.
                short8 u2 = *reinterpret_cast<const short8*>(uptr2 + n * 128);
                acc[j] = __builtin_amdgcn_mfma_f32_16x16x32_bf16(a2v, u2, zero4, 0, 0, 0);
            }
#pragma unroll
            for (int j = 0; j < 4; ++j) {
                const int n = tt + 4 * j;
                short8 u0 = *reinterpret_cast<const short8*>(uptr + (n * 2 + 0) * 512);
                short8 u1 = *reinterpret_cast<const short8*>(uptr + (n * 2 + 1) * 512);
                acc[j] = __builtin_amdgcn_mfma_f32_16x16x32_bf16(a0v, u0, acc[j], 0, 0, 0);
                acc[j] = __builtin_amdgcn_mfma_f32_16x16x32_bf16(a1v, u1, acc[j], 0, 0, 0);
            }
            // ea=e^{-zi}, ef=e^{-zf}, eg=e^{-2zg}, eo=e^{-zo}
            // c' update: c'n = sf*c' + (K2*eg - K2)*rcp((1+ea)(1+eg)); ec = exp2(c'n)
#pragma unroll
            for (int r = 0; r < 4; ++r) {
                float ea = __builtin_amdgcn_exp2f(acc[0][r]);
                float ef = __builtin_amdgcn_exp2f(acc[1][r]);
                float eg = __builtin_amdgcn_exp2f(acc[2][r]);
                float eo = __builtin_amdgcn_exp2f(acc[3][r]);
                float sf = __builtin_amdgcn_rcpf(1.0f + ef);
                float sg = fmaf(eg, K2, -K2) *
                    __builtin_amdgcn_rcpf((1.0f + ea) * (1.0f + eg));
                float cn = fmaf(sf, c_[tt][r], sg);
                c_[tt][r] = cn;
                float ec = __builtin_amdgcn_exp2f(cn);
                float hn = (1.0f - ec) *
                    __builtin_amdgcn_rcpf((1.0f + eo) * (1.0f + ec));
                if (save_h) h_[tt][r] = hn;
                hwptr[r * 72 + tt * 16] = f2bf(hn);
            }
        }
        LGKM_FENCE();   // h writes ordered before next step + sched region cap
    };

    // ---- warmup: 96 steps, x from this wave's LDS windows (1 read/step) ----
#pragma unroll 1
    for (int w = 0; w < NWIN; ++w) {
        if (w != 0) stage_x(w);   // prior step's fence ordered old-window reads
#pragma unroll 1
        for (int tl = 0; tl < WIN; ++tl)
            lstm_step(x_lds[wv][c4][tl], false);
    }

    // rebuild h_ (f32) from the bf16 LDS copy once after warmup
#pragma unroll
    for (int tt = 0; tt < 4; ++tt)
#pragma unroll
        for (int r = 0; r < 4; ++r)
            h_[tt][r] = bf2f((&h_lds[wv][0][0])[(hi * 4 + r) * 72 + tt * 16 + c4]);

    // hoist Wd for this lane's cols (decode-only registers)
    float wdc[4][2];
#pragma unroll
    for (int tt = 0; tt < 4; ++tt) {
        wdc[tt][0] = wdc_lds[tt][0][c4];
        wdc[tt][1] = wdc_lds[tt][1][c4];
    }

    // ---- decode: pred = h@Wd + bd, butterfly over the 16-lane col group ----
    auto make_pred = [&](float* p0, float* p1) {
#pragma unroll
        for (int r = 0; r < 4; ++r) {
            float a0 = 0.f, a1 = 0.f;
#pragma unroll
            for (int tt = 0; tt < 4; ++tt) {
                a0 = fmaf(h_[tt][r], wdc[tt][0], a0);
                a1 = fmaf(h_[tt][r], wdc[tt][1], a1);
            }
            p0[r] = a0; p1[r] = a1;
        }
#pragma unroll
        for (int m = 1; m < 16; m <<= 1)
#pragma unroll
            for (int r = 0; r < 4; ++r) {
                p0[r] += __shfl_xor(p0[r], m, 64);
                p1[r] += __shfl_xor(p1[r], m, 64);
            }
#pragma unroll
        for (int r = 0; r < 4; ++r) { p0[r] += bd0; p1[r] += bd1; }
    };
    // fetch row c4's pred from the lane group that owns it; pack bf16 pair
    auto build_xp = [&](const float* p0, const float* p1) -> unsigned {
        int srcl = (c4 >> 2) << 4;   // lane with hi = c4>>2 (col 0 of its group)
        float a  = __shfl(p0[0], srcl, 64), b2 = __shfl(p0[1], srcl, 64);
        float cc = __shfl(p0[2], srcl, 64), d  = __shfl(p0[3], srcl, 64);
        float e  = __shfl(p1[0], srcl, 64), f  = __shfl(p1[1], srcl, 64);
        float g  = __shfl(p1[2], srcl, 64), h2 = __shfl(p1[3], srcl, 64);
        int rr = c4 & 3;
        float q0 = (rr & 2) ? ((rr & 1) ? d  : cc) : ((rr & 1) ? b2 : a);
        float q1 = (rr & 2) ? ((rr & 1) ? h2 : g)  : ((rr & 1) ? f  : e);
        return pkbf(q0, q1);
    };
    // stash pred bf16 in this wave's (dead) x window for the final writeout
    auto store_pred = [&](int s, const float* p0, const float* p1) {
        if (c4 == 0) {
#pragma unroll
            for (int r = 0; r < 4; ++r)
                x_lds[wv][hi * 4 + r][s] = pkbf(p0[r], p1[r]);
        }
    };

    float p0[4], p1[4];
    make_pred(p0, p1);
    store_pred(0, p0, p1);
#pragma unroll 1
    for (int s = 1; s < SOUT; ++s) {
        lstm_step(build_xp(p0, p1), true);
        make_pred(p0, p1);
        store_pred(s, p0, p1);
    }
    LGKM_FENCE();   // all pred stashes of this wave visible to this wave

    // ---- per-wave coalesced writeout: 16 rows x 48 floats ----
#pragma unroll
    for (int m = 0; m < 6; ++m) {
        unsigned u = x_lds[wv][xrow][xq * 6 + m];
        *reinterpret_cast<float2*>(
            gout + (size_t)(row0 + xrow) * (SOUT * 2) + xq * 12 + m * 2) =
            make_float2(bf2f((short)(u & 0xFFFFu)), bf2f((short)(u >> 16)));
    }
}

extern "C" void kernel_launch(void* const* d_in, const int* in_sizes, int n_in,
                              void* d_out, int out_size, void* d_ws, size_t ws_size,
                              hipStream_t stream) {
    const float* gin  = (const float*)d_in[0];
    const float* gW   = (const float*)d_in[1];
    const float* gU   = (const float*)d_in[2];
    const float* gb   = (const float*)d_in[3];
    const float* gWd  = (const float*)d_in[4];
    const float* gbd  = (const float*)d_in[5];
    float* gout = (float*)d_out;

    const int B = in_sizes[0] / (TWARM * 2);
    const int blocks = (B + 127) / 128;
    lstm_ar_kernel<<<blocks, 512, 0, stream>>>(gin, gW, gU, gb, gWd, gbd, gout, B);
}